// Round 2
// baseline (1346.412 us; speedup 1.0000x reference)
//
#include <hip/hip_runtime.h>
#include <hip/hip_bf16.h>

#define HIDDEN 2048
#define NHEADS 16
#define HEADD  128
#define BATCH  4
#define SEQ    2048
#define MROWS  (BATCH*SEQ)   // 8192
#define NQKV   (3*HIDDEN)    // 6144

typedef __attribute__((ext_vector_type(8))) short bf16x8;
typedef __attribute__((ext_vector_type(4))) float f32x4;

__device__ inline unsigned short f2bf(float f) {
  unsigned int u = __builtin_bit_cast(unsigned int, f);
  u += 0x7FFF + ((u >> 16) & 1);           // RNE
  return (unsigned short)(u >> 16);
}

__device__ inline void async16(const void* g, void* s) {
  __builtin_amdgcn_global_load_lds(
      (__attribute__((address_space(1))) void*)(g),
      (__attribute__((address_space(3))) void*)(s), 16, 0, 0);
}

#define PH_BAR() asm volatile("s_barrier" ::: "memory")
#define LGKM0()  asm volatile("s_waitcnt lgkmcnt(0)" ::: "memory")
#define VMC6()   asm volatile("s_waitcnt vmcnt(6)" ::: "memory")
#define VMC0()   asm volatile("s_waitcnt vmcnt(0)" ::: "memory")

// ---------------- fp32 -> bf16 conversion (8 elems/thread) ----------------
__global__ __launch_bounds__(256)
void cvt_f32_bf16(const float* __restrict__ in, unsigned short* __restrict__ out, int n) {
  int i = (blockIdx.x * 256 + threadIdx.x) * 8;
  if (i + 8 <= n) {
    float4 a = *(const float4*)&in[i];
    float4 b = *(const float4*)&in[i + 4];
    unsigned short o[8];
    o[0] = f2bf(a.x); o[1] = f2bf(a.y); o[2] = f2bf(a.z); o[3] = f2bf(a.w);
    o[4] = f2bf(b.x); o[5] = f2bf(b.y); o[6] = f2bf(b.z); o[7] = f2bf(b.w);
    *(uint4*)&out[i] = *(uint4*)o;
  }
}

// ---------------- 256x256 8-phase NT GEMM (unchanged this round) ----------
#define MFMA_QUAD(AB, NB, AF, BF)                                           \
  _Pragma("unroll")                                                         \
  for (int mi = 0; mi < 4; ++mi)                                            \
    _Pragma("unroll")                                                       \
    for (int e = 0; e < 2; ++e)                                             \
      _Pragma("unroll")                                                     \
      for (int ks = 0; ks < 2; ++ks)                                        \
        acc[(AB) + mi][(NB) + e] = __builtin_amdgcn_mfma_f32_16x16x32_bf16( \
            AF[mi][ks], BF[e][ks], acc[(AB) + mi][(NB) + e], 0, 0, 0);

#define RD_A(DST, BUF, H)                                                   \
  _Pragma("unroll")                                                         \
  for (int mi = 0; mi < 4; ++mi) {                                          \
    DST[mi][0] = rdA(BUF, H, mi, 0);                                        \
    DST[mi][1] = rdA(BUF, H, mi, 1);                                        \
  }

#define RD_B(DST, BUF, H)                                                   \
  _Pragma("unroll")                                                         \
  for (int e = 0; e < 2; ++e) {                                             \
    DST[e][0] = rdB(BUF, H, e, 0);                                          \
    DST[e][1] = rdB(BUF, H, e, 1);                                          \
  }

template<int OUT_BF16>
__global__ __launch_bounds__(512, 2)
void gemm256(const unsigned short* __restrict__ A,   // [M][K] bf16
             const unsigned short* __restrict__ Bw,  // [N][K] bf16
             const float* __restrict__ bias,         // [N] fp32
             void* __restrict__ Cout, int M, int N, int K) {
  __shared__ __align__(16) unsigned short L[2][2][2][8192];  // 128 KiB

  const int t = threadIdx.x;
  const int lane = t & 63, wv = t >> 6;
  const int r = lane & 15, q = lane >> 4;
  const int wm = wv >> 2, wn = wv & 3;
  const int r7 = r & 7;

  const int gx = gridDim.x;
  const int nwg = gx * (int)gridDim.y;
  const int id = (int)blockIdx.y * gx + (int)blockIdx.x;
  const int swz = (id & 7) * (nwg >> 3) + (id >> 3);
  const int m0 = (swz / gx) * 256;
  const int n0 = (swz % gx) * 256;

  const int sub = t >> 3;
  const int cb = (t & 7) ^ (sub & 7);
  unsigned offA[2][2], offB[2][2];  // [h][ld], element offsets
#pragma unroll
  for (int ld = 0; ld < 2; ++ld) {
    int row = ld * 64 + sub;
    int fs = row >> 4, r16 = row & 15;
    int gA = (fs & 3) | ((fs >> 2) << 3);
    int gB = (fs & 1) | ((fs >> 1) << 2);
#pragma unroll
    for (int h = 0; h < 2; ++h) {
      offA[h][ld] = (unsigned)(m0 + (gA | (h << 2)) * 16 + r16) * (unsigned)K + cb * 8;
      offB[h][ld] = (unsigned)(n0 + (gB | (h << 1)) * 16 + r16) * (unsigned)K + cb * 8;
    }
  }

  auto stgA = [&](int buf, int h, int tile) {
    async16(A + (size_t)(offA[h][0] + (unsigned)tile * 64), &L[buf][0][h][t * 8]);
    async16(A + (size_t)(offA[h][1] + (unsigned)tile * 64), &L[buf][0][h][4096 + t * 8]);
  };
  auto stgB = [&](int buf, int h, int tile) {
    async16(Bw + (size_t)(offB[h][0] + (unsigned)tile * 64), &L[buf][1][h][t * 8]);
    async16(Bw + (size_t)(offB[h][1] + (unsigned)tile * 64), &L[buf][1][h][4096 + t * 8]);
  };
  auto rdA = [&](int buf, int h, int mi, int ks) -> bf16x8 {
    int row = (wm * 4 + mi) * 16 + r;
    int c = (ks * 4 + q) ^ r7;
    return *(const bf16x8*)&L[buf][0][h][row * 64 + c * 8];
  };
  auto rdB = [&](int buf, int h, int e, int ks) -> bf16x8 {
    int row = (wn * 2 + e) * 16 + r;
    int c = (ks * 4 + q) ^ r7;
    return *(const bf16x8*)&L[buf][1][h][row * 64 + c * 8];
  };

  f32x4 acc[8][4] = {};
  bf16x8 a0[4][2], a1[4][2], b0[2][2], b1[2][2];

  stgA(0, 0, 0); stgB(0, 0, 0); stgA(0, 1, 0); stgB(0, 1, 0);
  stgA(1, 0, 1); stgB(1, 0, 1); stgA(1, 1, 1);
  VMC6(); PH_BAR();

  const int NT = K >> 6;
  const int NITER = K >> 7;
#pragma unroll 1
  for (int i = 0; i < NITER; ++i) {
    const int ta = 2 * i + 1;
    int tb = 2 * i + 2; if (tb > NT - 1) tb = NT - 1;
    int tc = 2 * i + 3; if (tc > NT - 1) tc = NT - 1;

    RD_A(a0, 0, 0); RD_B(b0, 0, 0);
    stgB(1, 1, ta);
    PH_BAR(); LGKM0(); __builtin_amdgcn_s_setprio(1);
    MFMA_QUAD(0, 0, a0, b0);
    __builtin_amdgcn_s_setprio(0); PH_BAR();

    RD_A(a1, 0, 1);
    stgA(0, 0, tb);
    PH_BAR(); LGKM0(); __builtin_amdgcn_s_setprio(1);
    MFMA_QUAD(4, 0, a1, b0);
    __builtin_amdgcn_s_setprio(0); PH_BAR();

    RD_B(b1, 0, 1);
    stgB(0, 0, tb);
    PH_BAR(); LGKM0(); __builtin_amdgcn_s_setprio(1);
    MFMA_QUAD(4, 2, a1, b1);
    __builtin_amdgcn_s_setprio(0); PH_BAR();

    stgA(0, 1, tb);
    PH_BAR(); LGKM0(); __builtin_amdgcn_s_setprio(1);
    MFMA_QUAD(0, 2, a0, b1);
    __builtin_amdgcn_s_setprio(0); VMC6(); PH_BAR();

    RD_A(a0, 1, 0); RD_B(b0, 1, 0);
    stgB(0, 1, tb);
    PH_BAR(); LGKM0(); __builtin_amdgcn_s_setprio(1);
    MFMA_QUAD(0, 0, a0, b0);
    __builtin_amdgcn_s_setprio(0); PH_BAR();

    RD_A(a1, 1, 1);
    stgA(1, 0, tc);
    PH_BAR(); LGKM0(); __builtin_amdgcn_s_setprio(1);
    MFMA_QUAD(4, 0, a1, b0);
    __builtin_amdgcn_s_setprio(0); PH_BAR();

    RD_B(b1, 1, 1);
    stgB(1, 0, tc);
    PH_BAR(); LGKM0(); __builtin_amdgcn_s_setprio(1);
    MFMA_QUAD(4, 2, a1, b1);
    __builtin_amdgcn_s_setprio(0); PH_BAR();

    stgA(1, 1, tc);
    PH_BAR(); LGKM0(); __builtin_amdgcn_s_setprio(1);
    MFMA_QUAD(0, 2, a0, b1);
    __builtin_amdgcn_s_setprio(0); VMC6(); PH_BAR();
  }
  VMC0();

  float bv[4];
#pragma unroll
  for (int ni = 0; ni < 4; ++ni) bv[ni] = bias[n0 + (wn * 4 + ni) * 16 + r];
#pragma unroll
  for (int ai = 0; ai < 8; ++ai) {
    int grow = m0 + (wm * 8 + ai) * 16 + q * 4;
#pragma unroll
    for (int ni = 0; ni < 4; ++ni) {
      int gcol = n0 + (wn * 4 + ni) * 16 + r;
#pragma unroll
      for (int rr = 0; rr < 4; ++rr) {
        float v = acc[ai][ni][rr] + bv[ni];
        if (OUT_BF16)
          ((unsigned short*)Cout)[(size_t)(grow + rr) * N + gcol] = f2bf(v);
        else
          ((float*)Cout)[(size_t)(grow + rr) * N + gcol] = v;
      }
    }
  }
}

// ---------------- causal flash attention, split-KV -------------------------
// Fixed-max softmax => partial (accO, lsum) over disjoint KV ranges combine
// additively.  qt<=7: single chunk, direct bf16 write (old path).  qt>=8:
// 2 chunks of <=16 kv-tiles, f32 atomicAdd partials into outF(d_out) +
// lsumB; attn_norm divides and emits bf16.  Ps overlays Ks (K dead after
// QK^T; extra barrier) => LDS 32KB, 4 blocks/CU.
__global__ __launch_bounds__(256, 4)
void flash_attn(const unsigned short* __restrict__ qkv,  // [8192][6144] bf16
                unsigned short* __restrict__ attn,       // [8192][2048] bf16
                float* __restrict__ outF,                // [8192][2048] f32 partials
                float* __restrict__ lsumB)               // [4][1024][16] f32
{
  __shared__ __align__(16) unsigned short Ks[64][128];   // 16 KB (Ps overlays)
  __shared__ __align__(16) unsigned short Vt[128][64];   // 16 KB

  const int t = threadIdx.x;
  const int lane = t & 63, wv = t >> 6;
  const int r = lane & 15, q = lane >> 4;
  const int b = blockIdx.y >> 4, h = blockIdx.y & 15;

  // heavy-first chunk mapping: f<16 -> qt 15..8 (2 chunks), f>=16 -> qt 7..0
  int f = (int)blockIdx.x, qt, c;
  if (f < 16) { qt = 15 - (f >> 1); c = f & 1; }
  else        { qt = 23 - f;        c = 0; }
  const int q0 = qt * 128;
  const int t0 = c * 16;
  int t1 = 2 * qt + 2; if (t1 > t0 + 16) t1 = t0 + 16;

  unsigned short* Ps = &Ks[0][0] + wv * 2048;  // per-wave [32][64] overlay

  const size_t rs = NQKV;
  const unsigned short* qbase = qkv + (size_t)(b * SEQ) * rs + h * HEADD;
  const unsigned short* kbase = qbase + HIDDEN;
  const unsigned short* vbase = qbase + 2 * HIDDEN;

  bf16x8 qf[2][4];
  for (int i = 0; i < 2; ++i)
    for (int ks = 0; ks < 4; ++ks)
      qf[i][ks] = *(const bf16x8*)(qbase +
          (size_t)(q0 + wv * 32 + i * 16 + r) * rs + ks * 32 + q * 8);

  f32x4 accO[2][8] = {};
  float lsum[2][4] = {};

  const int diag0 = 2 * qt;
  const float sc2 = 0.08838834764831845f * 1.4426950408889634f;

  const int koct = t & 15, krb = t >> 4;
  const int bd4 = t & 15, bkv4 = t >> 4;

  uint4 kreg[4], vreg[4];
  for (int s = 0; s < 4; ++s)
    kreg[s] = *(const uint4*)(kbase + (size_t)(t0 * 64 + krb + 16 * s) * rs + koct * 8);
  for (int jr = 0; jr < 4; ++jr)
    vreg[jr] = *(const uint4*)(vbase + (size_t)(t0 * 64 + bkv4 * 4 + jr) * rs + bd4 * 8);

  for (int tk = t0; tk < t1; ++tk) {
    __syncthreads();  // prior step's LDS reads (incl. Ps=Ks region) done
    for (int s = 0; s < 4; ++s) {
      int row = krb + 16 * s;
      int cbk = koct ^ (row & 7);
      *(uint4*)&Ks[row][cbk * 8] = kreg[s];
    }
    for (int jj = 0; jj < 8; ++jj) {
      int d = bd4 * 8 + jj;
      int cbk = (bkv4 >> 1) ^ jj ^ (bd4 & 7);
      unsigned short tmp[4];
      for (int jr = 0; jr < 4; ++jr)
        tmp[jr] = ((const unsigned short*)&vreg[jr])[jj];
      *(uint2*)&Vt[d][cbk * 8 + (bkv4 & 1) * 4] = *(const uint2*)tmp;
    }
    __syncthreads();
    if (tk + 1 < t1) {
      for (int s = 0; s < 4; ++s)
        kreg[s] = *(const uint4*)(kbase + (size_t)((tk + 1) * 64 + krb + 16 * s) * rs + koct * 8);
      for (int jr = 0; jr < 4; ++jr)
        vreg[jr] = *(const uint4*)(vbase + (size_t)((tk + 1) * 64 + bkv4 * 4 + jr) * rs + bd4 * 8);
    }

    // --- QK^T ---
    f32x4 s[2][4] = {};
    __builtin_amdgcn_s_setprio(1);
    for (int ks = 0; ks < 4; ++ks) {
      bf16x8 bk[4];
      for (int j = 0; j < 4; ++j) {
        int row = j * 16 + r;
        int cbk = (ks * 4 + q) ^ (r & 7);
        bk[j] = *(const bf16x8*)&Ks[row][cbk * 8];
      }
      for (int i = 0; i < 2; ++i)
        for (int j = 0; j < 4; ++j)
          s[i][j] = __builtin_amdgcn_mfma_f32_16x16x32_bf16(qf[i][ks], bk[j], s[i][j], 0, 0, 0);
    }
    __builtin_amdgcn_s_setprio(0);
    __syncthreads();  // all waves done reading Ks before Ps overlay writes

    const bool diag = (tk >= diag0);
    for (int i = 0; i < 2; ++i) {
      float pvv[4][4];
      for (int j = 0; j < 4; ++j)
        for (int rr = 0; rr < 4; ++rr) {
          float v = s[i][j][rr] * sc2;
          if (diag) {
            int kvp = tk * 64 + j * 16 + r;
            int qp = q0 + wv * 32 + i * 16 + q * 4 + rr;
            if (kvp > qp) v = -1e30f;
          }
          float p = __builtin_amdgcn_exp2f(v);
          pvv[j][rr] = p;
          lsum[i][rr] += p;
        }
      for (int j = 0; j < 4; ++j)
        for (int rr = 0; rr < 4; ++rr) {
          int m = i * 16 + q * 4 + rr;
          int k = j * 16 + r;
          int cbk = (k >> 3) ^ (m & 7);
          Ps[m * 64 + cbk * 8 + (k & 7)] = f2bf(pvv[j][rr]);
        }
    }

    // --- P(32x64) @ V(64x128), Ps slice is wave-private ---
    __builtin_amdgcn_s_setprio(1);
    for (int ks2 = 0; ks2 < 2; ++ks2) {
      bf16x8 ap[2];
      for (int i = 0; i < 2; ++i) {
        int m = i * 16 + r;
        int cbk = (ks2 * 4 + q) ^ (r & 7);
        ap[i] = *(const bf16x8*)&Ps[m * 64 + cbk * 8];
      }
      for (int n = 0; n < 8; ++n) {
        int dd = n * 16 + r;
        int cbk = (ks2 * 4 + q) ^ (r & 7) ^ ((n * 2 + (r >> 3)) & 7);
        bf16x8 bvv = *(const bf16x8*)&Vt[dd][cbk * 8];
        for (int i = 0; i < 2; ++i)
          accO[i][n] = __builtin_amdgcn_mfma_f32_16x16x32_bf16(ap[i], bvv, accO[i][n], 0, 0, 0);
      }
    }
    __builtin_amdgcn_s_setprio(0);
  }

  for (int i = 0; i < 2; ++i)
    for (int rr = 0; rr < 4; ++rr) {
      float l = lsum[i][rr];
      for (int off = 1; off < 16; off <<= 1)
        l += __shfl_xor(l, off, 64);
      lsum[i][rr] = l;
    }

  if (qt < 8) {
    // single chunk: normalize and write bf16 directly
    for (int i = 0; i < 2; ++i)
      for (int rr = 0; rr < 4; ++rr) {
        int row = q0 + wv * 32 + i * 16 + q * 4 + rr;
        float inv = 1.0f / lsum[i][rr];
        size_t obase = (size_t)(b * SEQ + row) * HIDDEN + h * HEADD;
        for (int n = 0; n < 8; ++n)
          attn[obase + n * 16 + r] = f2bf(accO[i][n][rr] * inv);
      }
  } else {
    // partial: atomic-accumulate un-normalized sums
    for (int i = 0; i < 2; ++i)
      for (int rr = 0; rr < 4; ++rr) {
        int row = q0 + wv * 32 + i * 16 + q * 4 + rr;  // 1024..2047
        if (r == 0)
          unsafeAtomicAdd(&lsumB[(size_t)((b << 10) + row - 1024) * 16 + h], lsum[i][rr]);
        size_t obase = (size_t)(b * SEQ + row) * HIDDEN + h * HEADD;
        for (int n = 0; n < 8; ++n)
          unsafeAtomicAdd(&outF[obase + n * 16 + r], accO[i][n][rr]);
      }
  }
}

// normalize qt>=8 rows: attn = bf16(outF / lsum)
__global__ __launch_bounds__(256)
void attn_norm(const float* __restrict__ outF, const float* __restrict__ lsumB,
               unsigned short* __restrict__ attn) {
  int j = (blockIdx.x * 256 + threadIdx.x) * 8;   // over 4*1024*2048
  int b = j >> 21;
  int rl = (j >> 11) & 1023;
  int col = j & 2047;
  int h = col >> 7;
  float inv = 1.0f / lsumB[(size_t)((b << 10) + rl) * 16 + h];
  size_t base = (size_t)((b << 11) + 1024 + rl) * 2048 + col;
  float4 a = *(const float4*)&outF[base];
  float4 c4 = *(const float4*)&outF[base + 4];
  unsigned short o[8];
  o[0] = f2bf(a.x * inv);  o[1] = f2bf(a.y * inv);
  o[2] = f2bf(a.z * inv);  o[3] = f2bf(a.w * inv);
  o[4] = f2bf(c4.x * inv); o[5] = f2bf(c4.y * inv);
  o[6] = f2bf(c4.z * inv); o[7] = f2bf(c4.w * inv);
  *(uint4*)&attn[base] = *(uint4*)o;
}

// ---------------------------------------------------------------------------
extern "C" void kernel_launch(void* const* d_in, const int* in_sizes, int n_in,
                              void* d_out, int out_size, void* d_ws, size_t ws_size,
                              hipStream_t stream) {
  const float* hs      = (const float*)d_in[0];
  const float* w_qkv   = (const float*)d_in[1];
  const float* b_qkv   = (const float*)d_in[2];
  const float* w_dense = (const float*)d_in[3];
  const float* b_dense = (const float*)d_in[4];

  char* ws = (char*)d_ws;
  unsigned short* hsb  = (unsigned short*)ws;                            // 32 MB (reused as attn)
  unsigned short* wqb  = (unsigned short*)(ws + 33554432);               // 24 MB region
  unsigned short* qkvb = (unsigned short*)(ws + 33554432 + 25165824);    // 96 MB
  unsigned short* attnb = hsb;
  unsigned short* wdb   = wqb;                                           // 8 MB at region base
  float* lsumB = (float*)(ws + 33554432 + 16777216);                     // 256 KB at region+16MB
  float* outF  = (float*)d_out;                                          // 64 MB f32 partial acc

  cvt_f32_bf16<<<MROWS * HIDDEN / 2048, 256, 0, stream>>>(hs, hsb, MROWS * HIDDEN);
  cvt_f32_bf16<<<NQKV * HIDDEN / 2048, 256, 0, stream>>>(w_qkv, wqb, NQKV * HIDDEN);

  gemm256<1><<<dim3(NQKV / 256, MROWS / 256), 512, 0, stream>>>(
      hsb, wqb, b_qkv, qkvb, MROWS, NQKV, HIDDEN);

  // zero the partial-accumulation rows (local rows 1024..2047 of each batch)
  for (int b = 0; b < 4; ++b)
    hipMemsetAsync((char*)d_out + (size_t)(b * 2048 + 1024) * 2048 * 4, 0,
                   (size_t)1024 * 2048 * 4, stream);
  hipMemsetAsync(lsumB, 0, (size_t)4 * 1024 * 16 * 4, stream);

  flash_attn<<<dim3(24, BATCH * NHEADS), 256, 0, stream>>>(qkvb, attnb, outF, lsumB);

  cvt_f32_bf16<<<HIDDEN * HIDDEN / 2048, 256, 0, stream>>>(w_dense, wdb, HIDDEN * HIDDEN);

  attn_norm<<<4096, 256, 0, stream>>>(outF, lsumB, attnb);

  gemm256<0><<<dim3(HIDDEN / 256, MROWS / 256), 512, 0, stream>>>(
      attnb, wdb, b_dense, d_out, MROWS, HIDDEN, HIDDEN);
}

// Round 3
// 597.526 us; speedup vs baseline: 2.2533x; 2.2533x over previous
//
#include <hip/hip_runtime.h>
#include <hip/hip_bf16.h>

#define HIDDEN 2048
#define NHEADS 16
#define HEADD  128
#define BATCH  4
#define SEQ    2048
#define MROWS  (BATCH*SEQ)   // 8192
#define NQKV   (3*HIDDEN)    // 6144

typedef __attribute__((ext_vector_type(8))) short bf16x8;
typedef __attribute__((ext_vector_type(4))) float f32x4;

__device__ inline unsigned short f2bf(float f) {
  unsigned int u = __builtin_bit_cast(unsigned int, f);
  u += 0x7FFF + ((u >> 16) & 1);           // RNE
  return (unsigned short)(u >> 16);
}

__device__ inline void async16(const void* g, void* s) {
  __builtin_amdgcn_global_load_lds(
      (__attribute__((address_space(1))) void*)(g),
      (__attribute__((address_space(3))) void*)(s), 16, 0, 0);
}

#define PH_BAR() asm volatile("s_barrier" ::: "memory")
#define LGKM0()  asm volatile("s_waitcnt lgkmcnt(0)" ::: "memory")
#define VMC6()   asm volatile("s_waitcnt vmcnt(6)" ::: "memory")
#define VMC0()   asm volatile("s_waitcnt vmcnt(0)" ::: "memory")

// ---------------- fp32 -> bf16 conversion (8 elems/thread) ----------------
__global__ __launch_bounds__(256)
void cvt_f32_bf16(const float* __restrict__ in, unsigned short* __restrict__ out, int n) {
  int i = (blockIdx.x * 256 + threadIdx.x) * 8;
  if (i + 8 <= n) {
    float4 a = *(const float4*)&in[i];
    float4 b = *(const float4*)&in[i + 4];
    unsigned short o[8];
    o[0] = f2bf(a.x); o[1] = f2bf(a.y); o[2] = f2bf(a.z); o[3] = f2bf(a.w);
    o[4] = f2bf(b.x); o[5] = f2bf(b.y); o[6] = f2bf(b.z); o[7] = f2bf(b.w);
    *(uint4*)&out[i] = *(uint4*)o;
  }
}

// ---------------- 256x256 8-phase NT GEMM (unchanged) ---------------------
#define MFMA_QUAD(AB, NB, AF, BF)                                           \
  _Pragma("unroll")                                                         \
  for (int mi = 0; mi < 4; ++mi)                                            \
    _Pragma("unroll")                                                       \
    for (int e = 0; e < 2; ++e)                                             \
      _Pragma("unroll")                                                     \
      for (int ks = 0; ks < 2; ++ks)                                        \
        acc[(AB) + mi][(NB) + e] = __builtin_amdgcn_mfma_f32_16x16x32_bf16( \
            AF[mi][ks], BF[e][ks], acc[(AB) + mi][(NB) + e], 0, 0, 0);

#define RD_A(DST, BUF, H)                                                   \
  _Pragma("unroll")                                                         \
  for (int mi = 0; mi < 4; ++mi) {                                          \
    DST[mi][0] = rdA(BUF, H, mi, 0);                                        \
    DST[mi][1] = rdA(BUF, H, mi, 1);                                        \
  }

#define RD_B(DST, BUF, H)                                                   \
  _Pragma("unroll")                                                         \
  for (int e = 0; e < 2; ++e) {                                             \
    DST[e][0] = rdB(BUF, H, e, 0);                                          \
    DST[e][1] = rdB(BUF, H, e, 1);                                          \
  }

template<int OUT_BF16>
__global__ __launch_bounds__(512, 2)
void gemm256(const unsigned short* __restrict__ A,   // [M][K] bf16
             const unsigned short* __restrict__ Bw,  // [N][K] bf16
             const float* __restrict__ bias,         // [N] fp32
             void* __restrict__ Cout, int M, int N, int K) {
  __shared__ __align__(16) unsigned short L[2][2][2][8192];  // 128 KiB

  const int t = threadIdx.x;
  const int lane = t & 63, wv = t >> 6;
  const int r = lane & 15, q = lane >> 4;
  const int wm = wv >> 2, wn = wv & 3;
  const int r7 = r & 7;

  const int gx = gridDim.x;
  const int nwg = gx * (int)gridDim.y;
  const int id = (int)blockIdx.y * gx + (int)blockIdx.x;
  const int swz = (id & 7) * (nwg >> 3) + (id >> 3);
  const int m0 = (swz / gx) * 256;
  const int n0 = (swz % gx) * 256;

  const int sub = t >> 3;
  const int cb = (t & 7) ^ (sub & 7);
  unsigned offA[2][2], offB[2][2];  // [h][ld], element offsets
#pragma unroll
  for (int ld = 0; ld < 2; ++ld) {
    int row = ld * 64 + sub;
    int fs = row >> 4, r16 = row & 15;
    int gA = (fs & 3) | ((fs >> 2) << 3);
    int gB = (fs & 1) | ((fs >> 1) << 2);
#pragma unroll
    for (int h = 0; h < 2; ++h) {
      offA[h][ld] = (unsigned)(m0 + (gA | (h << 2)) * 16 + r16) * (unsigned)K + cb * 8;
      offB[h][ld] = (unsigned)(n0 + (gB | (h << 1)) * 16 + r16) * (unsigned)K + cb * 8;
    }
  }

  auto stgA = [&](int buf, int h, int tile) {
    async16(A + (size_t)(offA[h][0] + (unsigned)tile * 64), &L[buf][0][h][t * 8]);
    async16(A + (size_t)(offA[h][1] + (unsigned)tile * 64), &L[buf][0][h][4096 + t * 8]);
  };
  auto stgB = [&](int buf, int h, int tile) {
    async16(Bw + (size_t)(offB[h][0] + (unsigned)tile * 64), &L[buf][1][h][t * 8]);
    async16(Bw + (size_t)(offB[h][1] + (unsigned)tile * 64), &L[buf][1][h][4096 + t * 8]);
  };
  auto rdA = [&](int buf, int h, int mi, int ks) -> bf16x8 {
    int row = (wm * 4 + mi) * 16 + r;
    int c = (ks * 4 + q) ^ r7;
    return *(const bf16x8*)&L[buf][0][h][row * 64 + c * 8];
  };
  auto rdB = [&](int buf, int h, int e, int ks) -> bf16x8 {
    int row = (wn * 2 + e) * 16 + r;
    int c = (ks * 4 + q) ^ r7;
    return *(const bf16x8*)&L[buf][1][h][row * 64 + c * 8];
  };

  f32x4 acc[8][4] = {};
  bf16x8 a0[4][2], a1[4][2], b0[2][2], b1[2][2];

  stgA(0, 0, 0); stgB(0, 0, 0); stgA(0, 1, 0); stgB(0, 1, 0);
  stgA(1, 0, 1); stgB(1, 0, 1); stgA(1, 1, 1);
  VMC6(); PH_BAR();

  const int NT = K >> 6;
  const int NITER = K >> 7;
#pragma unroll 1
  for (int i = 0; i < NITER; ++i) {
    const int ta = 2 * i + 1;
    int tb = 2 * i + 2; if (tb > NT - 1) tb = NT - 1;
    int tc = 2 * i + 3; if (tc > NT - 1) tc = NT - 1;

    RD_A(a0, 0, 0); RD_B(b0, 0, 0);
    stgB(1, 1, ta);
    PH_BAR(); LGKM0(); __builtin_amdgcn_s_setprio(1);
    MFMA_QUAD(0, 0, a0, b0);
    __builtin_amdgcn_s_setprio(0); PH_BAR();

    RD_A(a1, 0, 1);
    stgA(0, 0, tb);
    PH_BAR(); LGKM0(); __builtin_amdgcn_s_setprio(1);
    MFMA_QUAD(4, 0, a1, b0);
    __builtin_amdgcn_s_setprio(0); PH_BAR();

    RD_B(b1, 0, 1);
    stgB(0, 0, tb);
    PH_BAR(); LGKM0(); __builtin_amdgcn_s_setprio(1);
    MFMA_QUAD(4, 2, a1, b1);
    __builtin_amdgcn_s_setprio(0); PH_BAR();

    stgA(0, 1, tb);
    PH_BAR(); LGKM0(); __builtin_amdgcn_s_setprio(1);
    MFMA_QUAD(0, 2, a0, b1);
    __builtin_amdgcn_s_setprio(0); VMC6(); PH_BAR();

    RD_A(a0, 1, 0); RD_B(b0, 1, 0);
    stgB(0, 1, tb);
    PH_BAR(); LGKM0(); __builtin_amdgcn_s_setprio(1);
    MFMA_QUAD(0, 0, a0, b0);
    __builtin_amdgcn_s_setprio(0); PH_BAR();

    RD_A(a1, 1, 1);
    stgA(1, 0, tc);
    PH_BAR(); LGKM0(); __builtin_amdgcn_s_setprio(1);
    MFMA_QUAD(4, 0, a1, b0);
    __builtin_amdgcn_s_setprio(0); PH_BAR();

    RD_B(b1, 1, 1);
    stgB(1, 0, tc);
    PH_BAR(); LGKM0(); __builtin_amdgcn_s_setprio(1);
    MFMA_QUAD(4, 2, a1, b1);
    __builtin_amdgcn_s_setprio(0); PH_BAR();

    stgA(1, 1, tc);
    PH_BAR(); LGKM0(); __builtin_amdgcn_s_setprio(1);
    MFMA_QUAD(0, 2, a0, b1);
    __builtin_amdgcn_s_setprio(0); VMC6(); PH_BAR();
  }
  VMC0();

  float bv[4];
#pragma unroll
  for (int ni = 0; ni < 4; ++ni) bv[ni] = bias[n0 + (wn * 4 + ni) * 16 + r];
#pragma unroll
  for (int ai = 0; ai < 8; ++ai) {
    int grow = m0 + (wm * 8 + ai) * 16 + q * 4;
#pragma unroll
    for (int ni = 0; ni < 4; ++ni) {
      int gcol = n0 + (wn * 4 + ni) * 16 + r;
#pragma unroll
      for (int rr = 0; rr < 4; ++rr) {
        float v = acc[ai][ni][rr] + bv[ni];
        if (OUT_BF16)
          ((unsigned short*)Cout)[(size_t)(grow + rr) * N + gcol] = f2bf(v);
        else
          ((float*)Cout)[(size_t)(grow + rr) * N + gcol] = v;
      }
    }
  }
}

// ---------------- causal flash attention, split-KV, no atomics ------------
// Fixed-max softmax => partials over disjoint KV ranges combine additively.
// qt<=7 (<=16 kv-tiles): single chunk, normalize + direct bf16 write.
// qt>=8: 2 chunks (c0 = tiles 0..15, c1 = tiles 16..2qt+1); each chunk
// DETERMINISTICALLY writes its un-normalized accO (f32) to a private slot
// of outP = d_out viewed as [2][4][1024][2048], and its lsum to
// lsumB[2][4][1024][16].  attn_norm merges: bf16((P0+P1)/(l0+l1)).
// Ps overlays Ks (K dead after QK^T) => LDS 32KB.  launch_bounds (256,2)
// keeps VGPR=128 codegen (round-2's (256,4) forced 64 VGPR -> spill thrash).
__global__ __launch_bounds__(256, 2)
void flash_attn(const unsigned short* __restrict__ qkv,  // [8192][6144] bf16
                unsigned short* __restrict__ attn,       // [8192][2048] bf16
                float* __restrict__ outP,                // [2][4][1024][2048] f32
                float* __restrict__ lsumB)               // [2][4][1024][16] f32
{
  __shared__ __align__(16) unsigned short Ks[64][128];   // 16 KB (Ps overlays)
  __shared__ __align__(16) unsigned short Vt[128][64];   // 16 KB

  const int t = threadIdx.x;
  const int lane = t & 63, wv = t >> 6;
  const int r = lane & 15, q = lane >> 4;
  const int b = blockIdx.y >> 4, h = blockIdx.y & 15;

  // heavy-first: f 0..7 -> qt 15..8 chunk0 (16 steps each);
  // f 8..15 -> qt 15..8 chunk1 (16..2 steps); f 16..23 -> qt 7..0 (16..2).
  int f = (int)blockIdx.x, qt, c;
  if (f < 8)       { qt = 15 - f; c = 0; }
  else if (f < 16) { qt = 23 - f; c = 1; }
  else             { qt = 23 - f; c = 0; }
  const int q0 = qt * 128;
  const int t0 = c * 16;
  int t1 = 2 * qt + 2; if (t1 > t0 + 16) t1 = t0 + 16;

  unsigned short* Ps = &Ks[0][0] + wv * 2048;  // per-wave [32][64] overlay

  const size_t rs = NQKV;
  const unsigned short* qbase = qkv + (size_t)(b * SEQ) * rs + h * HEADD;
  const unsigned short* kbase = qbase + HIDDEN;
  const unsigned short* vbase = qbase + 2 * HIDDEN;

  bf16x8 qf[2][4];
  for (int i = 0; i < 2; ++i)
    for (int ks = 0; ks < 4; ++ks)
      qf[i][ks] = *(const bf16x8*)(qbase +
          (size_t)(q0 + wv * 32 + i * 16 + r) * rs + ks * 32 + q * 8);

  f32x4 accO[2][8] = {};
  float lsum[2][4] = {};

  const int diag0 = 2 * qt;
  const float sc2 = 0.08838834764831845f * 1.4426950408889634f;

  const int koct = t & 15, krb = t >> 4;
  const int bd4 = t & 15, bkv4 = t >> 4;

  uint4 kreg[4], vreg[4];
  for (int s = 0; s < 4; ++s)
    kreg[s] = *(const uint4*)(kbase + (size_t)(t0 * 64 + krb + 16 * s) * rs + koct * 8);
  for (int jr = 0; jr < 4; ++jr)
    vreg[jr] = *(const uint4*)(vbase + (size_t)(t0 * 64 + bkv4 * 4 + jr) * rs + bd4 * 8);

  for (int tk = t0; tk < t1; ++tk) {
    __syncthreads();  // prior step's LDS reads (incl. Ps=Ks region) done
    for (int s = 0; s < 4; ++s) {
      int row = krb + 16 * s;
      int cbk = koct ^ (row & 7);
      *(uint4*)&Ks[row][cbk * 8] = kreg[s];
    }
    for (int jj = 0; jj < 8; ++jj) {
      int d = bd4 * 8 + jj;
      int cbk = (bkv4 >> 1) ^ jj ^ (bd4 & 7);
      unsigned short tmp[4];
      for (int jr = 0; jr < 4; ++jr)
        tmp[jr] = ((const unsigned short*)&vreg[jr])[jj];
      *(uint2*)&Vt[d][cbk * 8 + (bkv4 & 1) * 4] = *(const uint2*)tmp;
    }
    __syncthreads();
    if (tk + 1 < t1) {
      for (int s = 0; s < 4; ++s)
        kreg[s] = *(const uint4*)(kbase + (size_t)((tk + 1) * 64 + krb + 16 * s) * rs + koct * 8);
      for (int jr = 0; jr < 4; ++jr)
        vreg[jr] = *(const uint4*)(vbase + (size_t)((tk + 1) * 64 + bkv4 * 4 + jr) * rs + bd4 * 8);
    }

    // --- QK^T ---
    f32x4 s[2][4] = {};
    __builtin_amdgcn_s_setprio(1);
    for (int ks = 0; ks < 4; ++ks) {
      bf16x8 bk[4];
      for (int j = 0; j < 4; ++j) {
        int row = j * 16 + r;
        int cbk = (ks * 4 + q) ^ (r & 7);
        bk[j] = *(const bf16x8*)&Ks[row][cbk * 8];
      }
      for (int i = 0; i < 2; ++i)
        for (int j = 0; j < 4; ++j)
          s[i][j] = __builtin_amdgcn_mfma_f32_16x16x32_bf16(qf[i][ks], bk[j], s[i][j], 0, 0, 0);
    }
    __builtin_amdgcn_s_setprio(0);
    __syncthreads();  // all waves done reading Ks before Ps overlay writes

    const bool diag = (tk >= diag0);
    for (int i = 0; i < 2; ++i) {
      float pvv[4][4];
      for (int j = 0; j < 4; ++j)
        for (int rr = 0; rr < 4; ++rr) {
          float v = s[i][j][rr] * sc2;
          if (diag) {
            int kvp = tk * 64 + j * 16 + r;
            int qp = q0 + wv * 32 + i * 16 + q * 4 + rr;
            if (kvp > qp) v = -1e30f;
          }
          float p = __builtin_amdgcn_exp2f(v);
          pvv[j][rr] = p;
          lsum[i][rr] += p;
        }
      for (int j = 0; j < 4; ++j)
        for (int rr = 0; rr < 4; ++rr) {
          int m = i * 16 + q * 4 + rr;
          int k = j * 16 + r;
          int cbk = (k >> 3) ^ (m & 7);
          Ps[m * 64 + cbk * 8 + (k & 7)] = f2bf(pvv[j][rr]);
        }
    }

    // --- P(32x64) @ V(64x128), Ps slice is wave-private ---
    __builtin_amdgcn_s_setprio(1);
    for (int ks2 = 0; ks2 < 2; ++ks2) {
      bf16x8 ap[2];
      for (int i = 0; i < 2; ++i) {
        int m = i * 16 + r;
        int cbk = (ks2 * 4 + q) ^ (r & 7);
        ap[i] = *(const bf16x8*)&Ps[m * 64 + cbk * 8];
      }
      for (int n = 0; n < 8; ++n) {
        int dd = n * 16 + r;
        int cbk = (ks2 * 4 + q) ^ (r & 7) ^ ((n * 2 + (r >> 3)) & 7);
        bf16x8 bvv = *(const bf16x8*)&Vt[dd][cbk * 8];
        for (int i = 0; i < 2; ++i)
          accO[i][n] = __builtin_amdgcn_mfma_f32_16x16x32_bf16(ap[i], bvv, accO[i][n], 0, 0, 0);
      }
    }
    __builtin_amdgcn_s_setprio(0);
  }

  for (int i = 0; i < 2; ++i)
    for (int rr = 0; rr < 4; ++rr) {
      float l = lsum[i][rr];
      for (int off = 1; off < 16; off <<= 1)
        l += __shfl_xor(l, off, 64);
      lsum[i][rr] = l;
    }

  if (qt < 8) {
    // single chunk: normalize and write bf16 directly
    for (int i = 0; i < 2; ++i)
      for (int rr = 0; rr < 4; ++rr) {
        int row = q0 + wv * 32 + i * 16 + q * 4 + rr;
        float inv = 1.0f / lsum[i][rr];
        size_t obase = (size_t)(b * SEQ + row) * HIDDEN + h * HEADD;
        for (int n = 0; n < 8; ++n)
          attn[obase + n * 16 + r] = f2bf(accO[i][n][rr] * inv);
      }
  } else {
    // partial: plain (non-atomic) writes to this chunk's private slot
    const int cb4 = c * 4 + b;
    for (int i = 0; i < 2; ++i)
      for (int rr = 0; rr < 4; ++rr) {
        int row = q0 + wv * 32 + i * 16 + q * 4 + rr;  // 1024..2047
        int rl = row - 1024;
        if (r == 0)
          lsumB[(size_t)(cb4 * 1024 + rl) * 16 + h] = lsum[i][rr];
        size_t obase = (size_t)(cb4 * 1024 + rl) * 2048 + h * HEADD;
        for (int n = 0; n < 8; ++n)
          outP[obase + n * 16 + r] = accO[i][n][rr];
      }
  }
}

// merge the two KV-chunk partials for rows 1024..2047 of each batch:
// attn = bf16((P0 + P1) / (l0 + l1))
__global__ __launch_bounds__(256)
void attn_norm(const float* __restrict__ outP, const float* __restrict__ lsumB,
               unsigned short* __restrict__ attn) {
  size_t j = ((size_t)blockIdx.x * 256 + threadIdx.x) * 8;  // over 4*1024*2048
  int b = (int)(j >> 21);
  int rl = (int)(j >> 11) & 1023;
  int col = (int)j & 2047;
  int h = col >> 7;
  float l = lsumB[(size_t)(b * 1024 + rl) * 16 + h]
          + lsumB[(size_t)((4 + b) * 1024 + rl) * 16 + h];
  float inv = 1.0f / l;
  size_t p0 = (size_t)(b * 1024 + rl) * 2048 + col;
  size_t p1 = p0 + (size_t)4 * 1024 * 2048;
  float4 a0 = *(const float4*)&outP[p0];
  float4 a1 = *(const float4*)&outP[p0 + 4];
  float4 c0 = *(const float4*)&outP[p1];
  float4 c1 = *(const float4*)&outP[p1 + 4];
  unsigned short o[8];
  o[0] = f2bf((a0.x + c0.x) * inv); o[1] = f2bf((a0.y + c0.y) * inv);
  o[2] = f2bf((a0.z + c0.z) * inv); o[3] = f2bf((a0.w + c0.w) * inv);
  o[4] = f2bf((a1.x + c1.x) * inv); o[5] = f2bf((a1.y + c1.y) * inv);
  o[6] = f2bf((a1.z + c1.z) * inv); o[7] = f2bf((a1.w + c1.w) * inv);
  size_t base = (size_t)(b * 2048 + 1024 + rl) * 2048 + col;
  *(uint4*)&attn[base] = *(uint4*)o;
}

// ---------------------------------------------------------------------------
extern "C" void kernel_launch(void* const* d_in, const int* in_sizes, int n_in,
                              void* d_out, int out_size, void* d_ws, size_t ws_size,
                              hipStream_t stream) {
  const float* hs      = (const float*)d_in[0];
  const float* w_qkv   = (const float*)d_in[1];
  const float* b_qkv   = (const float*)d_in[2];
  const float* w_dense = (const float*)d_in[3];
  const float* b_dense = (const float*)d_in[4];

  char* ws = (char*)d_ws;
  unsigned short* hsb  = (unsigned short*)ws;                            // 32 MB (reused as attn)
  unsigned short* wqb  = (unsigned short*)(ws + 33554432);               // 24 MB region
  unsigned short* qkvb = (unsigned short*)(ws + 33554432 + 25165824);    // 96 MB
  unsigned short* attnb = hsb;
  unsigned short* wdb   = wqb;                                           // 8 MB at region base
  float* lsumB = (float*)(ws + 33554432 + 16777216);                     // 512 KB (w_qkv dead by then)
  float* outP  = (float*)d_out;                                          // 64 MB f32 partials (overwritten by gemm2)

  cvt_f32_bf16<<<MROWS * HIDDEN / 2048, 256, 0, stream>>>(hs, hsb, MROWS * HIDDEN);
  cvt_f32_bf16<<<NQKV * HIDDEN / 2048, 256, 0, stream>>>(w_qkv, wqb, NQKV * HIDDEN);

  gemm256<1><<<dim3(NQKV / 256, MROWS / 256), 512, 0, stream>>>(
      hsb, wqb, b_qkv, qkvb, MROWS, NQKV, HIDDEN);

  flash_attn<<<dim3(24, BATCH * NHEADS), 256, 0, stream>>>(qkvb, attnb, outP, lsumB);

  cvt_f32_bf16<<<HIDDEN * HIDDEN / 2048, 256, 0, stream>>>(w_dense, wdb, HIDDEN * HIDDEN);

  attn_norm<<<4096, 256, 0, stream>>>(outP, lsumB, attnb);

  gemm256<0><<<dim3(HIDDEN / 256, MROWS / 256), 512, 0, stream>>>(
      attnb, wdb, b_dense, d_out, MROWS, HIDDEN, HIDDEN);
}